// Round 9
// baseline (394.591 us; speedup 1.0000x reference)
//
#include <hip/hip_runtime.h>

#define N_NODES 100000
#define EDGES   1600000
#define CH      128
#define BN_EPS  1e-5f

#define BINS     782                  // ceil(100000 / 128)
#define CHUNKS   256                  // edge chunks for binning
#define CHUNK_E  (EDGES / CHUNKS)     // 6250, exact
#define HM       (BINS * CHUNKS)      // 200192 histogram cells
#define SCAN_NB  (HM / 256)           // 782, exact
#define NREP     64                   // BN-partial replicas
#define GEMM_BLOCKS 1563              // ceil(6250 wave-tiles / 4)

typedef __attribute__((ext_vector_type(8))) __bf16 bf16x8;
typedef __attribute__((ext_vector_type(4))) __bf16 bf16x4;
typedef __attribute__((ext_vector_type(2))) __bf16 bf16x2;
typedef __attribute__((ext_vector_type(4))) float  f32x4;

// ---------------------------------------------------------------------------
// d0: blocks 0..127 = W transpose+bf16 (both weights); 128..383 = histogram
// ---------------------------------------------------------------------------
__global__ __launch_bounds__(256) void wtrans_histo(const float* __restrict__ W1,
                                                    __bf16* __restrict__ Wt1,
                                                    const float* __restrict__ W2,
                                                    __bf16* __restrict__ Wt2,
                                                    const int* __restrict__ dst,
                                                    int* __restrict__ histo_g) {
    int b = blockIdx.x;
    int t = threadIdx.x;
    if (b < 128) {
        const float* W = (b < 64) ? W1 : W2;
        __bf16* Wt = (b < 64) ? Wt1 : Wt2;
        int idx = (b & 63) * 256 + t;
        int n = idx >> 7, k = idx & 127;
        Wt[idx] = (__bf16)W[k * 128 + n];
    } else {
        __shared__ int h[BINS];
        int chunk = b - 128;
        for (int i = t; i < BINS; i += 256) h[i] = 0;
        __syncthreads();
        int base = chunk * CHUNK_E;
        for (int i = t; i < CHUNK_E; i += 256)
            atomicAdd(&h[dst[base + i] >> 7], 1);
        __syncthreads();
        for (int i = t; i < BINS; i += 256)
            histo_g[i * CHUNKS + chunk] = h[i];
    }
}

// ---------------------------------------------------------------------------
// d1: blocks 0..1562 = GEMM1 (fp32 A, UNSCALED bf16 out) + zero gpart1;
//     blocks 1563..2344 = scan1 over histo_g
// ---------------------------------------------------------------------------
__global__ __launch_bounds__(256) void gemm1_scan(const float* __restrict__ A,
                                                  const __bf16* __restrict__ Wt,
                                                  __bf16* __restrict__ hs,
                                                  const int* __restrict__ histo_g,
                                                  int* __restrict__ scanned,
                                                  int* __restrict__ blocksum,
                                                  float* __restrict__ gpart1) {
    const int t = threadIdx.x;
    if (blockIdx.x < GEMM_BLOCKS) {
        if (blockIdx.x < NREP) gpart1[blockIdx.x * 256 + t] = 0.f;
        const int wave = t >> 6;
        const int rt = blockIdx.x * 4 + wave;
        if (rt >= N_NODES / 16) return;
        const int lane = t & 63;
        const int ln = lane & 15;
        const int quad = lane >> 4;
        const int arow = rt * 16 + ln;

        f32x4 acc[8];
        #pragma unroll
        for (int ct = 0; ct < 8; ++ct) acc[ct] = (f32x4){0.f, 0.f, 0.f, 0.f};

        #pragma unroll
        for (int k0 = 0; k0 < 128; k0 += 32) {
            const int k = k0 + quad * 8;
            float4 a0 = *(const float4*)(A + (size_t)arow * CH + k);
            float4 a1 = *(const float4*)(A + (size_t)arow * CH + k + 4);
            bf16x8 af;
            af[0] = (__bf16)a0.x; af[1] = (__bf16)a0.y;
            af[2] = (__bf16)a0.z; af[3] = (__bf16)a0.w;
            af[4] = (__bf16)a1.x; af[5] = (__bf16)a1.y;
            af[6] = (__bf16)a1.z; af[7] = (__bf16)a1.w;
            #pragma unroll
            for (int ct = 0; ct < 8; ++ct) {
                bf16x8 bfrag = *(const bf16x8*)(Wt + (size_t)(ct * 16 + ln) * CH + k);
                acc[ct] = __builtin_amdgcn_mfma_f32_16x16x32_bf16(af, bfrag, acc[ct], 0, 0, 0);
            }
        }
        #pragma unroll
        for (int r = 0; r < 4; ++r) {
            const int row_r = rt * 16 + quad * 4 + r;
            __bf16* orow = hs + (size_t)row_r * CH + ln;
            #pragma unroll
            for (int ct = 0; ct < 8; ++ct)
                orow[ct * 16] = (__bf16)acc[ct][r];
        }
    } else {
        __shared__ int sh[2][256];
        int sb = blockIdx.x - GEMM_BLOCKS;
        int i = sb * 256 + t;
        int v = histo_g[i];
        sh[0][t] = v;
        __syncthreads();
        int pp = 0;
        #pragma unroll
        for (int off = 1; off < 256; off <<= 1) {
            int val = sh[pp][t] + ((t >= off) ? sh[pp][t - off] : 0);
            sh[1 - pp][t] = val;
            pp = 1 - pp;
            __syncthreads();
        }
        int incl = sh[pp][t];
        scanned[i] = incl - v;
        if (t == 255) blocksum[sb] = incl;
    }
}

// ---------------------------------------------------------------------------
__global__ __launch_bounds__(1024) void scan2(int* __restrict__ blocksum) {
    __shared__ int sh[2][1024];
    int t = threadIdx.x;
    int v = (t < SCAN_NB) ? blocksum[t] : 0;
    sh[0][t] = v;
    __syncthreads();
    int pp = 0;
    #pragma unroll
    for (int off = 1; off < 1024; off <<= 1) {
        int val = sh[pp][t] + ((t >= off) ? sh[pp][t - off] : 0);
        sh[1 - pp][t] = val;
        pp = 1 - pp;
        __syncthreads();
    }
    if (t < SCAN_NB) blocksum[t] = sh[pp][t] - v;
}

__global__ __launch_bounds__(256) void scan3(int* __restrict__ scanned,
                                             const int* __restrict__ blocksum) {
    int i = blockIdx.x * 256 + threadIdx.x;
    scanned[i] += blocksum[blockIdx.x];
    if (i == HM - 1) scanned[HM] = EDGES;
}

// ---------------------------------------------------------------------------
__global__ __launch_bounds__(256) void place_kernel(const int* __restrict__ src,
                                                    const int* __restrict__ dst,
                                                    const int* __restrict__ scanned,
                                                    int* __restrict__ binned) {
    __shared__ int cur[BINS];
    int t = threadIdx.x;
    for (int b = t; b < BINS; b += 256)
        cur[b] = scanned[b * CHUNKS + blockIdx.x];
    __syncthreads();
    int base = blockIdx.x * CHUNK_E;
    for (int i = t; i < CHUNK_E; i += 256) {
        int d = dst[base + i];
        int s = src[base + i];
        int pos = atomicAdd(&cur[d >> 7], 1);
        binned[pos] = (s << 7) | (d & 127);
    }
}

// ---------------------------------------------------------------------------
__global__ __launch_bounds__(256) void bin_csr(const int* __restrict__ binned,
                                               const int* __restrict__ scanned,
                                               int* __restrict__ srcs,
                                               int* __restrict__ rowptr,
                                               float* __restrict__ dinv) {
    __shared__ int cnt[128];
    __shared__ int sc[2][128];
    __shared__ int base[128];
    __shared__ int cur[128];
    const int t = threadIdx.x;
    const int bin = blockIdx.x;
    if (t < 128) { cnt[t] = 0; cur[t] = 0; }
    __syncthreads();
    const int beg = scanned[bin * CHUNKS];
    const int end = scanned[bin * CHUNKS + CHUNKS];
    for (int e = beg + t; e < end; e += 256)
        atomicAdd(&cnt[binned[e] & 127], 1);
    __syncthreads();
    if (t < 128) sc[0][t] = cnt[t];
    __syncthreads();
    int pp = 0;
    #pragma unroll
    for (int off = 1; off < 128; off <<= 1) {
        if (t < 128) sc[1 - pp][t] = sc[pp][t] + ((t >= off) ? sc[pp][t - off] : 0);
        pp = 1 - pp;
        __syncthreads();
    }
    if (t < 128) {
        base[t] = beg + sc[pp][t] - cnt[t];
        int n = (bin << 7) + t;
        if (n < N_NODES) {
            rowptr[n] = base[t];
            dinv[n] = rsqrtf((float)cnt[t] + 1.0f);
        }
    }
    if (bin == 0 && t == 0) rowptr[N_NODES] = EDGES;
    __syncthreads();
    for (int e = beg + t; e < end; e += 256) {
        int p = binned[e];
        int dl = p & 127;
        int pos = base[dl] + atomicAdd(&cur[dl], 1);
        srcs[pos] = p >> 7;
    }
}

// ---------------------------------------------------------------------------
// pull-gather (R8 structure, UNSCALED hs): per-edge scalar dinv[src] loads,
// agg[n] = dinv[n]*(dinv[n]*hs[n] + sum_e dinv[src_e]*hs[src_e]); fused stats.
// ---------------------------------------------------------------------------
__global__ __launch_bounds__(256) void gather_agg(const __bf16* __restrict__ hs,
                                                  const int* __restrict__ srcs,
                                                  const int* __restrict__ rowptr,
                                                  const float* __restrict__ dinv,
                                                  __bf16* __restrict__ agg,
                                                  float* __restrict__ gpart) {
    __shared__ float red[4][64][4];
    const int wave = threadIdx.x >> 6;
    const int c2 = threadIdx.x & 63;
    const bf16x2* hp = (const bf16x2*)hs;

    float s0 = 0.f, ss0 = 0.f, s1 = 0.f, ss1 = 0.f;

    #pragma unroll
    for (int it = 0; it < 2; ++it) {
        const int n = __builtin_amdgcn_readfirstlane(blockIdx.x * 8 + wave * 2 + it);
        const int beg = rowptr[n];
        const int end = rowptr[n + 1];
        const float d = dinv[n];
        bf16x2 sv = hp[(size_t)n * 64 + c2];
        float ax = d * (float)sv[0], ay = d * (float)sv[1];
        int j = beg;
        for (; j + 8 <= end; j += 8) {
            int e0 = srcs[j + 0], e1 = srcs[j + 1], e2 = srcs[j + 2], e3 = srcs[j + 3];
            int e4 = srcs[j + 4], e5 = srcs[j + 5], e6 = srcs[j + 6], e7 = srcs[j + 7];
            float d0 = dinv[e0], d1 = dinv[e1], d2 = dinv[e2], d3 = dinv[e3];
            float d4 = dinv[e4], d5 = dinv[e5], d6 = dinv[e6], d7 = dinv[e7];
            bf16x2 v0 = hp[(size_t)e0 * 64 + c2];
            bf16x2 v1 = hp[(size_t)e1 * 64 + c2];
            bf16x2 v2 = hp[(size_t)e2 * 64 + c2];
            bf16x2 v3 = hp[(size_t)e3 * 64 + c2];
            bf16x2 v4 = hp[(size_t)e4 * 64 + c2];
            bf16x2 v5 = hp[(size_t)e5 * 64 + c2];
            bf16x2 v6 = hp[(size_t)e6 * 64 + c2];
            bf16x2 v7 = hp[(size_t)e7 * 64 + c2];
            ax = fmaf(d0, (float)v0[0], ax); ay = fmaf(d0, (float)v0[1], ay);
            ax = fmaf(d1, (float)v1[0], ax); ay = fmaf(d1, (float)v1[1], ay);
            ax = fmaf(d2, (float)v2[0], ax); ay = fmaf(d2, (float)v2[1], ay);
            ax = fmaf(d3, (float)v3[0], ax); ay = fmaf(d3, (float)v3[1], ay);
            ax = fmaf(d4, (float)v4[0], ax); ay = fmaf(d4, (float)v4[1], ay);
            ax = fmaf(d5, (float)v5[0], ax); ay = fmaf(d5, (float)v5[1], ay);
            ax = fmaf(d6, (float)v6[0], ax); ay = fmaf(d6, (float)v6[1], ay);
            ax = fmaf(d7, (float)v7[0], ax); ay = fmaf(d7, (float)v7[1], ay);
        }
        for (; j < end; ++j) {
            int e = srcs[j];
            float de = dinv[e];
            bf16x2 v = hp[(size_t)e * 64 + c2];
            ax = fmaf(de, (float)v[0], ax);
            ay = fmaf(de, (float)v[1], ay);
        }
        float ox = ax * d, oy = ay * d;
        bf16x2 o; o[0] = (__bf16)ox; o[1] = (__bf16)oy;
        ((bf16x2*)agg)[(size_t)n * 64 + c2] = o;
        s0 += ox; ss0 += ox * ox;
        s1 += oy; ss1 += oy * oy;
    }

    f32x4 rv; rv[0] = s0; rv[1] = ss0; rv[2] = s1; rv[3] = ss1;
    *(f32x4*)red[wave][c2] = rv;
    __syncthreads();
    const int t = threadIdx.x;
    float v = red[0][t >> 2][t & 3] + red[1][t >> 2][t & 3] +
              red[2][t >> 2][t & 3] + red[3][t >> 2][t & 3];
    atomicAdd(&gpart[(blockIdx.x & (NREP - 1)) * 256 + t], v);
}

// ---------------------------------------------------------------------------
// per-block gpart reduce -> scale/shift in LDS (128 channels)
// slot layout: gpart[r*256 + (c>>1)*4 + 2*(c&1) + {0,1}] = {sum, sumsq}
// ---------------------------------------------------------------------------
__device__ __forceinline__ void bn_reduce_lds(const float* __restrict__ gpart,
                                              const float* __restrict__ gamma,
                                              const float* __restrict__ beta,
                                              float* sc_s, float* sh_s) {
    const int t = threadIdx.x;
    if (t < 128) {
        int c2 = t >> 1, odd = t & 1;
        float s = 0.f, ss = 0.f;
        for (int r = 0; r < NREP; ++r) {
            s  += gpart[r * 256 + c2 * 4 + 2 * odd];
            ss += gpart[r * 256 + c2 * 4 + 2 * odd + 1];
        }
        const float invN = 1.0f / (float)N_NODES;
        float mu = s * invN;
        float var = ss * invN - mu * mu;
        float sc = gamma[t] * rsqrtf(var + BN_EPS);
        sc_s[t] = sc;
        sh_s[t] = beta[t] - mu * sc;
    }
    __syncthreads();
}

// ---------------------------------------------------------------------------
// d7: GEMM2 = per-block bn_final1 + zero gpart2 + bf16 A + fused BN1/relu,
//     UNSCALED bf16 out
// ---------------------------------------------------------------------------
__global__ __launch_bounds__(256) void gemm2_bn(const __bf16* __restrict__ A,
                                                const __bf16* __restrict__ Wt,
                                                const float* __restrict__ gpart1,
                                                const float* __restrict__ gamma,
                                                const float* __restrict__ beta,
                                                __bf16* __restrict__ hs,
                                                float* __restrict__ gpart2) {
    __shared__ float sc_s[128], sh_s[128];
    const int t = threadIdx.x;
    if (blockIdx.x < NREP) gpart2[blockIdx.x * 256 + t] = 0.f;
    bn_reduce_lds(gpart1, gamma, beta, sc_s, sh_s);

    const int wave = t >> 6;
    const int rt = blockIdx.x * 4 + wave;
    if (rt >= N_NODES / 16) return;
    const int lane = t & 63;
    const int ln = lane & 15;
    const int quad = lane >> 4;
    const int arow = rt * 16 + ln;

    f32x4 acc[8];
    #pragma unroll
    for (int ct = 0; ct < 8; ++ct) acc[ct] = (f32x4){0.f, 0.f, 0.f, 0.f};

    #pragma unroll
    for (int k0 = 0; k0 < 128; k0 += 32) {
        const int k = k0 + quad * 8;
        bf16x8 av = *(const bf16x8*)(A + (size_t)arow * CH + k);
        bf16x8 af;
        #pragma unroll
        for (int j = 0; j < 8; ++j)
            af[j] = (__bf16)fmaxf(fmaf((float)av[j], sc_s[k + j], sh_s[k + j]), 0.f);
        #pragma unroll
        for (int ct = 0; ct < 8; ++ct) {
            bf16x8 bfrag = *(const bf16x8*)(Wt + (size_t)(ct * 16 + ln) * CH + k);
            acc[ct] = __builtin_amdgcn_mfma_f32_16x16x32_bf16(af, bfrag, acc[ct], 0, 0, 0);
        }
    }

    #pragma unroll
    for (int r = 0; r < 4; ++r) {
        const int row_r = rt * 16 + quad * 4 + r;
        __bf16* orow = hs + (size_t)row_r * CH + ln;
        #pragma unroll
        for (int ct = 0; ct < 8; ++ct)
            orow[ct * 16] = (__bf16)acc[ct][r];
    }
}

// ---------------------------------------------------------------------------
// d9: epilogue = per-block bn_final2 + out = relu(agg*scale + shift + x)
// grid-stride over 3.2M float4 with 2048 blocks
// ---------------------------------------------------------------------------
__global__ __launch_bounds__(256) void epilogue_bn(const __bf16* __restrict__ v,
                                                   const float* __restrict__ gpart2,
                                                   const float* __restrict__ gamma,
                                                   const float* __restrict__ beta,
                                                   const float* __restrict__ xin,
                                                   float* __restrict__ outv) {
    __shared__ float sc_s[128], sh_s[128];
    bn_reduce_lds(gpart2, gamma, beta, sc_s, sh_s);

    const int total4 = N_NODES * 32;              // 3,200,000 float4
    for (int i = blockIdx.x * 256 + threadIdx.x; i < total4; i += 2048 * 256) {
        int cg = i & 31;
        bf16x4 a4 = ((const bf16x4*)v)[i];
        float4 r = ((const float4*)xin)[i];
        float4 a;
        a.x = fmaxf(fmaf((float)a4[0], sc_s[cg * 4 + 0], sh_s[cg * 4 + 0]) + r.x, 0.f);
        a.y = fmaxf(fmaf((float)a4[1], sc_s[cg * 4 + 1], sh_s[cg * 4 + 1]) + r.y, 0.f);
        a.z = fmaxf(fmaf((float)a4[2], sc_s[cg * 4 + 2], sh_s[cg * 4 + 2]) + r.z, 0.f);
        a.w = fmaxf(fmaf((float)a4[3], sc_s[cg * 4 + 3], sh_s[cg * 4 + 3]) + r.w, 0.f);
        ((float4*)outv)[i] = a;
    }
}

// ---------------------------------------------------------------------------
extern "C" void kernel_launch(void* const* d_in, const int* in_sizes, int n_in,
                              void* d_out, int out_size, void* d_ws, size_t ws_size,
                              hipStream_t stream) {
    const float* x      = (const float*)d_in[0];
    const float* W1     = (const float*)d_in[1];
    // b1/b2 cancel exactly inside BatchNorm (per-channel constant shift)
    const float* W2     = (const float*)d_in[3];
    const float* gamma2 = (const float*)d_in[5];
    const float* beta2  = (const float*)d_in[6];
    const int*   ei     = (const int*)d_in[7];    // [2, E] int32
    const int*   srcI   = ei;
    const int*   dstI   = ei + EDGES;
    float* out = (float*)d_out;

    char* ws = (char*)d_ws;
    __bf16* agg      = (__bf16*)(ws);                      // 25.6 MB
    __bf16* hs       = (__bf16*)(ws + 25600000);           // 25.6 MB
    int*    binned   = (int*)   (ws + 51200000);           // 6.4 MB
    int*    srcs     = (int*)   (ws + 57600000);           // 6.4 MB
    int*    histo_g  = (int*)   (ws + 64000000);           // 800,768 B
    int*    scanned  = (int*)   (ws + 64801024);           // (HM+1) ints
    int*    blocksum = (int*)   (ws + 65602048);           // 3,128 B
    float*  dinv     = (float*) (ws + 65605632);           // 400 KB
    int*    rowptr   = (int*)   (ws + 66005632);           // 400,004 B
    __bf16* Wt1      = (__bf16*)(ws + 66405888);           // 32 KB
    __bf16* Wt2      = (__bf16*)(ws + 66438656);           // 32 KB
    float*  gpart1   = (float*) (ws + 66471424);           // 64 KB
    float*  gpart2   = (float*) (ws + 66536960);           // 64 KB

    const int GATHER_BLOCKS = N_NODES / 8;                // 12500

    // d0: weight prep || bin histogram
    wtrans_histo<<<128 + CHUNKS, 256, 0, stream>>>(W1, Wt1, W2, Wt2, dstI, histo_g);
    // d1: GEMM1 (unscaled) + zero gpart1 || scan1
    gemm1_scan<<<GEMM_BLOCKS + SCAN_NB, 256, 0, stream>>>(x, Wt1, hs, histo_g,
                                                          scanned, blocksum, gpart1);
    scan2<<<1, 1024, 0, stream>>>(blocksum);
    scan3<<<SCAN_NB, 256, 0, stream>>>(scanned, blocksum);
    place_kernel<<<CHUNKS, 256, 0, stream>>>(srcI, dstI, scanned, binned);
    bin_csr<<<BINS, 256, 0, stream>>>(binned, scanned, srcs, rowptr, dinv);

    // conv1 aggregation (+ BN1 stats into gpart1)
    gather_agg<<<GATHER_BLOCKS, 256, 0, stream>>>(hs, srcs, rowptr, dinv, agg, gpart1);
    // conv2 GEMM (bn_final1 per-block + BN1-apply/relu fused) + zero gpart2
    gemm2_bn<<<GEMM_BLOCKS, 256, 0, stream>>>(agg, Wt2, gpart1, gamma2, beta2, hs, gpart2);
    // conv2 aggregation (+ BN2 stats into gpart2)
    gather_agg<<<GATHER_BLOCKS, 256, 0, stream>>>(hs, srcs, rowptr, dinv, agg, gpart2);
    // epilogue: bn_final2 per-block + BN2-apply + residual + relu
    epilogue_bn<<<2048, 256, 0, stream>>>(agg, gpart2, gamma2, beta2, x, out);
}